// Round 11
// baseline (168.506 us; speedup 1.0000x reference)
//
#include <hip/hip_runtime.h>

#define BB 16
#define CC 128
#define TT 128
#define HH 128
#define BC (BB*CC)   // 2048

typedef __attribute__((ext_vector_type(8))) short bf16x8;
typedef __attribute__((ext_vector_type(4))) float f32x4;

__device__ __forceinline__ unsigned short f2bf(float f) {
  union { float f; unsigned u; } v; v.f = f;
  unsigned u = v.u;
  u += 0x7FFFu + ((u >> 16) & 1u);   // round-to-nearest-even
  return (unsigned short)(u >> 16);
}

__device__ __forceinline__ bf16x8 pack8(f32x4 a, f32x4 b) {
  bf16x8 r;
  r[0] = (short)f2bf(a[0]); r[1] = (short)f2bf(a[1]);
  r[2] = (short)f2bf(a[2]); r[3] = (short)f2bf(a[3]);
  r[4] = (short)f2bf(b[0]); r[5] = (short)f2bf(b[1]);
  r[6] = (short)f2bf(b[2]); r[7] = (short)f2bf(b[3]);
  return r;
}

__device__ __forceinline__ float bf2f(unsigned short u) {
  union { unsigned u; float f; } v; v.u = ((unsigned)u) << 16; return v.f;
}

// ---- prep (unchanged from R9) ----------------------------------------------
__global__ __launch_bounds__(256) void prep_kernel(
    const float* __restrict__ Wt, const float* __restrict__ Wc, const float* __restrict__ Wa,
    const float* __restrict__ clone, const float* __restrict__ food,
    const float* __restrict__ bt, const float* __restrict__ bcl,
    const int* __restrict__ tmask, const int* __restrict__ cmask,
    unsigned short* __restrict__ W2sw, unsigned short* __restrict__ Wcsw,
    unsigned short* __restrict__ WaggT,
    float* __restrict__ cpt, float* __restrict__ cp1, float* __restrict__ cj2,
    unsigned short* __restrict__ agg,
    int* __restrict__ tidx, int* __restrict__ tcnt,
    int* __restrict__ cidx, int* __restrict__ ccnt) {
  const int blk = blockIdx.x, tid = threadIdx.x;
  if (blk < 48) {
    int i = blk * 256 + tid;
    if (i < 2048) {                       // thorn frags: 32 frags x 64 lanes
      int f = i >> 6, l = i & 63;
      int kt = f >> 3, n = f & 7;
      int ncol = n * 16 + (l & 15);
      int k0 = kt * 32 + (l >> 4) * 8;
      unsigned short o[8];
      #pragma unroll
      for (int e = 0; e < 8; ++e) o[e] = f2bf(Wt[(128 + k0 + e) * 128 + ncol]);
      *(uint4*)&W2sw[i * 8] = *(uint4*)o;
    } else if (i < 4096) {                // clone W3 frags: 32 frags x 64 lanes
      int j = i - 2048;
      int f = j >> 6, l = j & 63;
      int kt = f >> 3, n = f & 7;
      int ncol = n * 16 + (l & 15);
      int k0 = kt * 32 + (l >> 4) * 8;
      unsigned short o[8];
      #pragma unroll
      for (int e = 0; e < 8; ++e) o[e] = f2bf(Wc[(256 + k0 + e) * 128 + ncol]);
      *(uint4*)&Wcsw[j * 8] = *(uint4*)o;
    } else {                              // agg weights, plain [n][k] transpose
      int j = i - 4096;                   // [0, 8192)
      int n = j >> 6, k0 = (j & 63) * 8;
      unsigned short o[8];
      #pragma unroll
      for (int e = 0; e < 8; ++e) o[e] = f2bf(Wa[(k0 + e) * 128 + n]);
      *(uint4*)&WaggT[n * 512 + k0] = *(uint4*)o;
    }
  } else if (blk < 304) {
    // bias rows: 8 bc rows per block; 3 GEMVs per element
    const int bc0 = (blk - 48) * 8;
    __shared__ float cl[8][128];
    for (int i = tid; i < 1024; i += 256) cl[i >> 7][i & 127] = clone[bc0 * 128 + i];
    __syncthreads();
    const int k = tid & 127, r0 = (tid >> 7) * 4;
    float s1[4], s2[4], s3[4];
    #pragma unroll
    for (int r = 0; r < 4; ++r) { s1[r] = bt[k]; s2[r] = bcl[k]; s3[r] = 0.f; }
    #pragma unroll 4
    for (int h = 0; h < 128; ++h) {
      float w1 = Wt[h * 128 + k], w2 = Wc[h * 128 + k], w3 = Wc[(128 + h) * 128 + k];
      #pragma unroll
      for (int r = 0; r < 4; ++r) {
        float c = cl[r0 + r][h];
        s1[r] = fmaf(c, w1, s1[r]);
        s2[r] = fmaf(c, w2, s2[r]);
        s3[r] = fmaf(c, w3, s3[r]);
      }
    }
    #pragma unroll
    for (int r = 0; r < 4; ++r) {
      cpt[(bc0 + r0 + r) * 128 + k] = s1[r];
      cp1[(bc0 + r0 + r) * 128 + k] = s2[r];
      cj2[(bc0 + r0 + r) * 128 + k] = s3[r];
    }
    for (int i = tid; i < 1024; i += 256) {
      int r = i >> 7, kk = i & 127;
      agg[(size_t)(bc0 + r) * 512 + kk]       = f2bf(cl[r][kk]);
      agg[(size_t)(bc0 + r) * 512 + 128 + kk] = f2bf(food[bc0 * 128 + i]);
    }
  } else {
    // mask compaction: thread i<32: b=i>>1, which=i&1; serial scan of 128 entries
    if (tid < 32) {
      int b = tid >> 1, which = tid & 1;
      const int* m = which ? cmask : tmask;
      int* idx = which ? cidx : tidx;
      int c = 0;
      for (int i = 0; i < 128; ++i)
        if (m[b * 128 + i]) idx[b * 128 + c++] = i;
      if (which) ccnt[b] = c; else tcnt[b] = c;
    }
  }
}

// ---- fused branch kernel: blocks 0..255 clone, 256..511 thorn --------------
// Wave-owns-tile: wave w handles tile bc0+w ALONE, looping over the G =
// ceil(cnt/16) active row-groups of its tile with 1-deep register prefetch.
// Every wave has identical work regardless of cnt; NO per-tile barrier (only
// the staging barrier); per-wave shfl max reduction + direct agg store.
// Clone j-term added in epilogue from transposed+padded LDS cj2 (K=128 both).
__global__ __launch_bounds__(512, 4) void branch10(
    const float* __restrict__ trel, const float* __restrict__ crel,
    const float* __restrict__ cpt, const float* __restrict__ cp1,
    const float* __restrict__ cj2,
    const int* __restrict__ tidx, const int* __restrict__ tcnt,
    const int* __restrict__ cidx, const int* __restrict__ ccnt,
    const uint4* __restrict__ W2sw, const uint4* __restrict__ Wcsw,
    unsigned short* __restrict__ agg) {
  __shared__ uint4 Wlds[32 * 64];              // 32 KB
  __shared__ unsigned short cj2l[128][130];    // 32.5 KB, transposed [col][row]+pad
  __shared__ int idxl[128];

  const bool isClone = blockIdx.x < 256;
  const int tileIdx = blockIdx.x & 255;
  const float* __restrict__ rel     = isClone ? crel  : trel;
  const float* __restrict__ biasrow = isClone ? cp1   : cpt;
  const int*   __restrict__ idxg    = isClone ? cidx  : tidx;
  const uint4* __restrict__ Wsw     = isClone ? Wcsw  : W2sw;
  const int aggoff = isClone ? 384 : 256;

  const int tid = threadIdx.x;
  const int wave = tid >> 6, lane = tid & 63;
  const int l16 = lane & 15, lk = lane >> 4;
  const int bc0 = tileIdx << 3;               // 8 tiles per block
  const int b = bc0 >> 7;                     // same b for all 8 tiles
  const int cnt = (isClone ? ccnt : tcnt)[b];
  const int cl  = cnt > 0 ? cnt : 1;
  const int G   = (cnt + 15) >> 4;            // row-groups per tile

  for (int i = tid; i < 2048; i += 512) Wlds[i] = Wsw[i];
  if (tid < 128) idxl[tid] = idxg[b * 128 + tid];
  if (isClone) {                              // stage cj2[b] transposed as bf16
    const float* cg = cj2 + (size_t)b * 128 * 128;
    for (int i = tid; i < 2048; i += 512) {
      int r = i >> 4, c8 = (i & 15) * 8;
      f32x4 a0 = *(const f32x4*)(cg + r * 128 + c8);
      f32x4 a1 = *(const f32x4*)(cg + r * 128 + c8 + 4);
      bf16x8 p = pack8(a0, a1);
      #pragma unroll
      for (int e = 0; e < 8; ++e) cj2l[c8 + e][r] = (unsigned short)p[e];
    }
  }
  __syncthreads();                            // W, idx, cj2 ready (only barrier)

  const int bc = bc0 + wave;                  // this wave's tile
  const float* Rb = rel + (size_t)bc * 16384 + lk * 8;

  // per-wave bias (8 cols per lane), straight from global (L2)
  float bias[8];
  #pragma unroll
  for (int n = 0; n < 8; ++n) bias[n] = biasrow[bc * 128 + n * 16 + l16];

  float vmax[8];
  #pragma unroll
  for (int n = 0; n < 8; ++n) vmax[n] = 0.f;

  // prefetch row-group 0
  f32x4 pf[4][2];
  if (G > 0) {
    int rs = l16 < cl ? l16 : cl - 1;
    const float* Rt = Rb + idxl[rs] * 128;
    #pragma unroll
    for (int kt = 0; kt < 4; ++kt) {
      pf[kt][0] = *(const f32x4*)(Rt + kt * 32);
      pf[kt][1] = *(const f32x4*)(Rt + kt * 32 + 4);
    }
  }

  for (int i = 0; i < G; ++i) {
    bf16x8 afr[4];
    #pragma unroll
    for (int kt = 0; kt < 4; ++kt) afr[kt] = pack8(pf[kt][0], pf[kt][1]);

    // issue next row-group's loads: fly during MFMA + epilogue
    if (i + 1 < G) {
      int rs = (i + 1) * 16 + l16; if (rs >= cl) rs = cl - 1;
      const float* Rn = Rb + idxl[rs] * 128;
      #pragma unroll
      for (int kt = 0; kt < 4; ++kt) {
        pf[kt][0] = *(const f32x4*)(Rn + kt * 32);
        pf[kt][1] = *(const f32x4*)(Rn + kt * 32 + 4);
      }
    }

    f32x4 acc[8];
    #pragma unroll
    for (int n = 0; n < 8; ++n) acc[n] = (f32x4){0.f, 0.f, 0.f, 0.f};
    #pragma unroll
    for (int kt = 0; kt < 4; ++kt) {
      #pragma unroll
      for (int n = 0; n < 8; ++n) {
        bf16x8 bfr = *(const bf16x8*)&Wlds[(kt * 8 + n) * 64 + lane];
        acc[n] = __builtin_amdgcn_mfma_f32_16x16x32_bf16(afr[kt], bfr, acc[n], 0, 0, 0);
      }
    }

    if (isClone) {
      int rowj[4];                            // C/D row = lk*4+j (m89 layout)
      #pragma unroll
      for (int j = 0; j < 4; ++j) {
        int rs = i * 16 + lk * 4 + j; if (rs >= cl) rs = cl - 1;
        rowj[j] = idxl[rs];
      }
      #pragma unroll
      for (int n = 0; n < 8; ++n) {
        const int col = n * 16 + l16;
        #pragma unroll
        for (int j = 0; j < 4; ++j) {
          float x = acc[n][j] + bias[n] + bf2f(cj2l[col][rowj[j]]);
          vmax[n] = fmaxf(vmax[n], fmaxf(x, 0.f));
        }
      }
    } else {
      #pragma unroll
      for (int n = 0; n < 8; ++n) {
        #pragma unroll
        for (int j = 0; j < 4; ++j)
          vmax[n] = fmaxf(vmax[n], fmaxf(acc[n][j] + bias[n], 0.f));
      }
    }
  }

  // per-wave reduction across lk groups, direct store (no block barrier)
  unsigned short* aggw = agg + (size_t)bc * 512 + aggoff;
  #pragma unroll
  for (int n = 0; n < 8; ++n) {
    float v = vmax[n];
    v = fmaxf(v, __shfl_xor(v, 16));
    v = fmaxf(v, __shfl_xor(v, 32));
    if (lane < 16) aggw[n * 16 + lane] = f2bf(v);
  }
}

// ---- final: out = clone + relu(agg(2048x512) @ W_agg + b_agg) --------------
__global__ __launch_bounds__(256) void final_kernel(
    const unsigned short* __restrict__ agg, const unsigned short* __restrict__ WaggT,
    const float* __restrict__ clone, const float* __restrict__ bagg,
    float* __restrict__ out) {
  const int tid = threadIdx.x;
  const int wave = tid >> 6, lane = tid & 63;
  const int l16 = lane & 15, lk = lane >> 4;
  const int mrow = blockIdx.x * 16;

  f32x4 acc[2];
  acc[0] = (f32x4){0.f, 0.f, 0.f, 0.f};
  acc[1] = (f32x4){0.f, 0.f, 0.f, 0.f};
  #pragma unroll
  for (int kt = 0; kt < 16; ++kt) {
    bf16x8 a = *(const bf16x8*)(agg + (size_t)(mrow + l16) * 512 + kt * 32 + lk * 8);
    #pragma unroll
    for (int nn = 0; nn < 2; ++nn) {
      int ncol = (wave * 2 + nn) * 16 + l16;
      bf16x8 bfr = *(const bf16x8*)(WaggT + (size_t)ncol * 512 + kt * 32 + lk * 8);
      acc[nn] = __builtin_amdgcn_mfma_f32_16x16x32_bf16(a, bfr, acc[nn], 0, 0, 0);
    }
  }
  #pragma unroll
  for (int nn = 0; nn < 2; ++nn) {
    int col = (wave * 2 + nn) * 16 + l16;
    float bias = bagg[col];
    #pragma unroll
    for (int j = 0; j < 4; ++j) {
      int row = mrow + lk * 4 + j;
      out[row * 128 + col] = clone[row * 128 + col] + fmaxf(acc[nn][j] + bias, 0.f);
    }
  }
}

extern "C" void kernel_launch(void* const* d_in, const int* in_sizes, int n_in,
                              void* d_out, int out_size, void* d_ws, size_t ws_size,
                              hipStream_t stream) {
  const float* food  = (const float*)d_in[0];
  const float* trel  = (const float*)d_in[1];
  const float* clone = (const float*)d_in[2];
  const float* crel  = (const float*)d_in[3];
  const int*   tmask = (const int*)d_in[4];
  const int*   cmask = (const int*)d_in[5];
  const float* Wt    = (const float*)d_in[6];
  const float* bt    = (const float*)d_in[7];
  const float* Wc    = (const float*)d_in[8];
  const float* bcl   = (const float*)d_in[9];
  const float* Wa    = (const float*)d_in[10];
  const float* ba    = (const float*)d_in[11];
  float* out = (float*)d_out;

  char* w = (char*)d_ws;
  float* cpt = (float*)w;                      w += (size_t)BC * 128 * 4;
  float* cp1 = (float*)w;                      w += (size_t)BC * 128 * 4;
  float* cj2 = (float*)w;                      w += (size_t)BC * 128 * 4;
  unsigned short* W2sw  = (unsigned short*)w;  w += 32 * 64 * 8 * 2;     // 32 KB
  unsigned short* Wcsw  = (unsigned short*)w;  w += 32 * 64 * 8 * 2;     // 32 KB
  unsigned short* WaggT = (unsigned short*)w;  w += 128 * 512 * 2;       // 128 KB
  unsigned short* aggb  = (unsigned short*)w;  w += (size_t)BC * 512 * 2;
  int* tidx = (int*)w;                         w += 16 * 128 * 4;
  int* cidx = (int*)w;                         w += 16 * 128 * 4;
  int* tcnt = (int*)w;                         w += 16 * 4;
  int* ccnt = (int*)w;                         w += 16 * 4;

  prep_kernel<<<305, 256, 0, stream>>>(Wt, Wc, Wa, clone, food, bt, bcl,
                                       tmask, cmask,
                                       W2sw, Wcsw, WaggT, cpt, cp1, cj2, aggb,
                                       tidx, tcnt, cidx, ccnt);
  branch10<<<512, 512, 0, stream>>>(trel, crel, cpt, cp1, cj2,
                                    tidx, tcnt, cidx, ccnt,
                                    (const uint4*)W2sw, (const uint4*)Wcsw, aggb);
  final_kernel<<<128, 256, 0, stream>>>(aggb, WaggT, clone, ba, out);
}

// Round 12
// 73.854 us; speedup vs baseline: 2.2816x; 2.2816x over previous
//
#include <hip/hip_runtime.h>

#define BB 16
#define CC 128
#define TT 128
#define HH 128
#define BC (BB*CC)   // 2048

typedef __attribute__((ext_vector_type(8))) short bf16x8;
typedef __attribute__((ext_vector_type(4))) float f32x4;

__device__ __forceinline__ unsigned short f2bf(float f) {
  union { float f; unsigned u; } v; v.f = f;
  unsigned u = v.u;
  u += 0x7FFFu + ((u >> 16) & 1u);   // round-to-nearest-even
  return (unsigned short)(u >> 16);
}

__device__ __forceinline__ bf16x8 pack8(f32x4 a, f32x4 b) {
  bf16x8 r;
  r[0] = (short)f2bf(a[0]); r[1] = (short)f2bf(a[1]);
  r[2] = (short)f2bf(a[2]); r[3] = (short)f2bf(a[3]);
  r[4] = (short)f2bf(b[0]); r[5] = (short)f2bf(b[1]);
  r[6] = (short)f2bf(b[2]); r[7] = (short)f2bf(b[3]);
  return r;
}

__device__ __forceinline__ float bf2f(unsigned short u) {
  union { unsigned u; float f; } v; v.u = ((unsigned)u) << 16; return v.f;
}

// ---- prep (unchanged, validated) --------------------------------------------
__global__ __launch_bounds__(256) void prep_kernel(
    const float* __restrict__ Wt, const float* __restrict__ Wc, const float* __restrict__ Wa,
    const float* __restrict__ clone, const float* __restrict__ food,
    const float* __restrict__ bt, const float* __restrict__ bcl,
    const int* __restrict__ tmask, const int* __restrict__ cmask,
    unsigned short* __restrict__ W2sw, unsigned short* __restrict__ Wcsw,
    unsigned short* __restrict__ WaggT,
    float* __restrict__ cpt, float* __restrict__ cp1, float* __restrict__ cj2,
    unsigned short* __restrict__ agg,
    int* __restrict__ tidx, int* __restrict__ tcnt,
    int* __restrict__ cidx, int* __restrict__ ccnt) {
  const int blk = blockIdx.x, tid = threadIdx.x;
  if (blk < 48) {
    int i = blk * 256 + tid;
    if (i < 2048) {                       // thorn frags: 32 frags x 64 lanes
      int f = i >> 6, l = i & 63;
      int kt = f >> 3, n = f & 7;
      int ncol = n * 16 + (l & 15);
      int k0 = kt * 32 + (l >> 4) * 8;
      unsigned short o[8];
      #pragma unroll
      for (int e = 0; e < 8; ++e) o[e] = f2bf(Wt[(128 + k0 + e) * 128 + ncol]);
      *(uint4*)&W2sw[i * 8] = *(uint4*)o;
    } else if (i < 4096) {                // clone W3 frags: 32 frags x 64 lanes
      int j = i - 2048;
      int f = j >> 6, l = j & 63;
      int kt = f >> 3, n = f & 7;
      int ncol = n * 16 + (l & 15);
      int k0 = kt * 32 + (l >> 4) * 8;
      unsigned short o[8];
      #pragma unroll
      for (int e = 0; e < 8; ++e) o[e] = f2bf(Wc[(256 + k0 + e) * 128 + ncol]);
      *(uint4*)&Wcsw[j * 8] = *(uint4*)o;
    } else {                              // agg weights, plain [n][k] transpose
      int j = i - 4096;                   // [0, 8192)
      int n = j >> 6, k0 = (j & 63) * 8;
      unsigned short o[8];
      #pragma unroll
      for (int e = 0; e < 8; ++e) o[e] = f2bf(Wa[(k0 + e) * 128 + n]);
      *(uint4*)&WaggT[n * 512 + k0] = *(uint4*)o;
    }
  } else if (blk < 304) {
    // bias rows: 8 bc rows per block; 3 GEMVs per element
    const int bc0 = (blk - 48) * 8;
    __shared__ float cl[8][128];
    for (int i = tid; i < 1024; i += 256) cl[i >> 7][i & 127] = clone[bc0 * 128 + i];
    __syncthreads();
    const int k = tid & 127, r0 = (tid >> 7) * 4;
    float s1[4], s2[4], s3[4];
    #pragma unroll
    for (int r = 0; r < 4; ++r) { s1[r] = bt[k]; s2[r] = bcl[k]; s3[r] = 0.f; }
    #pragma unroll 4
    for (int h = 0; h < 128; ++h) {
      float w1 = Wt[h * 128 + k], w2 = Wc[h * 128 + k], w3 = Wc[(128 + h) * 128 + k];
      #pragma unroll
      for (int r = 0; r < 4; ++r) {
        float c = cl[r0 + r][h];
        s1[r] = fmaf(c, w1, s1[r]);
        s2[r] = fmaf(c, w2, s2[r]);
        s3[r] = fmaf(c, w3, s3[r]);
      }
    }
    #pragma unroll
    for (int r = 0; r < 4; ++r) {
      cpt[(bc0 + r0 + r) * 128 + k] = s1[r];
      cp1[(bc0 + r0 + r) * 128 + k] = s2[r];
      cj2[(bc0 + r0 + r) * 128 + k] = s3[r];
    }
    for (int i = tid; i < 1024; i += 256) {
      int r = i >> 7, kk = i & 127;
      agg[(size_t)(bc0 + r) * 512 + kk]       = f2bf(cl[r][kk]);
      agg[(size_t)(bc0 + r) * 512 + 128 + kk] = f2bf(food[bc0 * 128 + i]);
    }
  } else {
    // mask compaction: thread i<32: b=i>>1, which=i&1; serial scan of 128 entries
    if (tid < 32) {
      int b = tid >> 1, which = tid & 1;
      const int* m = which ? cmask : tmask;
      int* idx = which ? cidx : tidx;
      int c = 0;
      for (int i = 0; i < 128; ++i)
        if (m[b * 128 + i]) idx[b * 128 + c++] = i;
      if (which) ccnt[b] = c; else tcnt[b] = c;
    }
  }
}

// ---- fused branch kernel: blocks 0..255 clone, 256..511 thorn --------------
// branch9 + PINNED prefetch: asm memory clobber right after issuing next-tile
// loads stops the compiler from sinking them below the MFMA/epilogue, so HBM
// latency overlaps compute instead of stalling at the per-tile barrier.
__global__ __launch_bounds__(512, 4) void branch11(
    const float* __restrict__ trel, const float* __restrict__ crel,
    const float* __restrict__ cpt, const float* __restrict__ cp1,
    const float* __restrict__ cj2,
    const int* __restrict__ tidx, const int* __restrict__ tcnt,
    const int* __restrict__ cidx, const int* __restrict__ ccnt,
    const uint4* __restrict__ W2sw, const uint4* __restrict__ Wcsw,
    unsigned short* __restrict__ agg) {
  __shared__ uint4 Wlds[32 * 64];              // 32 KB
  __shared__ unsigned short cj2l[128][130];    // 32.5 KB, transposed [col][row]+pad
  __shared__ float redbuf[2][8][128];          // 8 KB, double-buffered
  __shared__ int idxl[128];
  __shared__ float biasl[8][128];              // 4 KB

  const bool isClone = blockIdx.x < 256;
  const int tileIdx = blockIdx.x & 255;
  const float* __restrict__ rel     = isClone ? crel  : trel;
  const float* __restrict__ biasrow = isClone ? cp1   : cpt;
  const int*   __restrict__ idxg    = isClone ? cidx  : tidx;
  const uint4* __restrict__ Wsw     = isClone ? Wcsw  : W2sw;
  const int aggoff = isClone ? 384 : 256;

  const int tid = threadIdx.x;
  const int wave = tid >> 6, lane = tid & 63;
  const int l16 = lane & 15, lk = lane >> 4;
  const int bc0 = tileIdx << 3;               // 8 tiles per block
  const int b = bc0 >> 7;                     // same b for all 8 tiles
  const int cnt = (isClone ? ccnt : tcnt)[b];
  const int cl  = cnt > 0 ? cnt : 1;
  const bool active = (wave * 16) < cnt;      // wave-uniform skip

  for (int i = tid; i < 2048; i += 512) Wlds[i] = Wsw[i];
  if (tid < 128) idxl[tid] = idxg[b * 128 + tid];
  #pragma unroll
  for (int i = 0; i < 2; ++i) {
    int q = i * 512 + tid;
    biasl[q >> 7][q & 127] = biasrow[bc0 * 128 + q];
  }
  if (isClone) {                              // stage cj2[b] transposed as bf16
    const float* cg = cj2 + (size_t)b * 128 * 128;
    for (int i = tid; i < 2048; i += 512) {
      int r = i >> 4, c8 = (i & 15) * 8;
      f32x4 a0 = *(const f32x4*)(cg + r * 128 + c8);
      f32x4 a1 = *(const f32x4*)(cg + r * 128 + c8 + 4);
      bf16x8 p = pack8(a0, a1);
      #pragma unroll
      for (int e = 0; e < 8; ++e) cj2l[c8 + e][r] = (unsigned short)p[e];
    }
  }
  __syncthreads();                            // W, idx, bias, cj2 ready

  // gathered A row for this lane (fixed across all 8 tiles)
  int rsel = wave * 16 + l16; if (rsel >= cl) rsel = cl - 1;
  const int row = active ? idxl[rsel] : 0;
  const float* R0 = rel + ((size_t)bc0 * 128 + row) * 128 + lk * 8;

  // epilogue row->orig-j map (clone only; C/D row = lk*4+j), fixed across tiles
  int rowj[4];
  if (isClone) {
    #pragma unroll
    for (int j = 0; j < 4; ++j) {
      int rs = wave * 16 + lk * 4 + j; if (rs >= cl) rs = cl - 1;
      rowj[j] = idxl[rs];
    }
  }

  // prefetch tile 0 (f32 in regs), pinned
  f32x4 pf[4][2];
  if (active) {
    #pragma unroll
    for (int kt = 0; kt < 4; ++kt) {
      pf[kt][0] = *(const f32x4*)(R0 + kt * 32);
      pf[kt][1] = *(const f32x4*)(R0 + kt * 32 + 4);
    }
    asm volatile("" ::: "memory");            // pin: issue before anything below
  }

  for (int t = 0; t < 8; ++t) {
    const int bc = bc0 + t;

    if (active) {
      bf16x8 afr[4];
      #pragma unroll
      for (int kt = 0; kt < 4; ++kt) afr[kt] = pack8(pf[kt][0], pf[kt][1]);

      // issue next tile's loads NOW; clobber stops the compiler sinking them
      if (t < 7) {
        const float* Rn = R0 + (size_t)(t + 1) * 16384;
        #pragma unroll
        for (int kt = 0; kt < 4; ++kt) {
          pf[kt][0] = *(const f32x4*)(Rn + kt * 32);
          pf[kt][1] = *(const f32x4*)(Rn + kt * 32 + 4);
        }
        asm volatile("" ::: "memory");        // pin: loads fly during MFMA+epilogue
      }

      f32x4 acc[8];
      #pragma unroll
      for (int n = 0; n < 8; ++n) acc[n] = (f32x4){0.f, 0.f, 0.f, 0.f};
      #pragma unroll
      for (int kt = 0; kt < 4; ++kt) {
        #pragma unroll
        for (int n = 0; n < 8; ++n) {
          bf16x8 bfr = *(const bf16x8*)&Wlds[(kt * 8 + n) * 64 + lane];
          acc[n] = __builtin_amdgcn_mfma_f32_16x16x32_bf16(afr[kt], bfr, acc[n], 0, 0, 0);
        }
      }

      // epilogue: bias (+ cj2 j-term for clone), relu, max over rows
      #pragma unroll
      for (int n = 0; n < 8; ++n) {
        const int col = n * 16 + l16;
        float bias = biasl[t][col];
        float m0 = 0.f;
        if (isClone) {
          #pragma unroll
          for (int j = 0; j < 4; ++j) {
            float x = acc[n][j] + bias + bf2f(cj2l[col][rowj[j]]);
            m0 = fmaxf(m0, fmaxf(x, 0.f));
          }
        } else {
          #pragma unroll
          for (int j = 0; j < 4; ++j)
            m0 = fmaxf(m0, fmaxf(acc[n][j] + bias, 0.f));
        }
        float v = fmaxf(m0, __shfl_xor(m0, 16));
        v = fmaxf(v, __shfl_xor(v, 32));
        if (lane < 16) redbuf[t & 1][wave][col] = v;
      }
    } else {
      // inactive wave: contribute zeros (relu >= 0 keeps max correct)
      if (lane < 16) {
        #pragma unroll
        for (int n = 0; n < 8; ++n) redbuf[t & 1][wave][n * 16 + lane] = 0.f;
      }
    }
    __syncthreads();
    if (tid < 128) {
      float v = redbuf[t & 1][0][tid];
      #pragma unroll
      for (int w2 = 1; w2 < 8; ++w2) v = fmaxf(v, redbuf[t & 1][w2][tid]);
      agg[(size_t)bc * 512 + aggoff + tid] = f2bf(v);
    }
    // no second barrier: next tile writes the other redbuf half
  }
}

// ---- final: out = clone + relu(agg(2048x512) @ W_agg + b_agg) --------------
__global__ __launch_bounds__(256) void final_kernel(
    const unsigned short* __restrict__ agg, const unsigned short* __restrict__ WaggT,
    const float* __restrict__ clone, const float* __restrict__ bagg,
    float* __restrict__ out) {
  const int tid = threadIdx.x;
  const int wave = tid >> 6, lane = tid & 63;
  const int l16 = lane & 15, lk = lane >> 4;
  const int mrow = blockIdx.x * 16;

  f32x4 acc[2];
  acc[0] = (f32x4){0.f, 0.f, 0.f, 0.f};
  acc[1] = (f32x4){0.f, 0.f, 0.f, 0.f};
  #pragma unroll
  for (int kt = 0; kt < 16; ++kt) {
    bf16x8 a = *(const bf16x8*)(agg + (size_t)(mrow + l16) * 512 + kt * 32 + lk * 8);
    #pragma unroll
    for (int nn = 0; nn < 2; ++nn) {
      int ncol = (wave * 2 + nn) * 16 + l16;
      bf16x8 bfr = *(const bf16x8*)(WaggT + (size_t)ncol * 512 + kt * 32 + lk * 8);
      acc[nn] = __builtin_amdgcn_mfma_f32_16x16x32_bf16(a, bfr, acc[nn], 0, 0, 0);
    }
  }
  #pragma unroll
  for (int nn = 0; nn < 2; ++nn) {
    int col = (wave * 2 + nn) * 16 + l16;
    float bias = bagg[col];
    #pragma unroll
    for (int j = 0; j < 4; ++j) {
      int row = mrow + lk * 4 + j;
      out[row * 128 + col] = clone[row * 128 + col] + fmaxf(acc[nn][j] + bias, 0.f);
    }
  }
}

extern "C" void kernel_launch(void* const* d_in, const int* in_sizes, int n_in,
                              void* d_out, int out_size, void* d_ws, size_t ws_size,
                              hipStream_t stream) {
  const float* food  = (const float*)d_in[0];
  const float* trel  = (const float*)d_in[1];
  const float* clone = (const float*)d_in[2];
  const float* crel  = (const float*)d_in[3];
  const int*   tmask = (const int*)d_in[4];
  const int*   cmask = (const int*)d_in[5];
  const float* Wt    = (const float*)d_in[6];
  const float* bt    = (const float*)d_in[7];
  const float* Wc    = (const float*)d_in[8];
  const float* bcl   = (const float*)d_in[9];
  const float* Wa    = (const float*)d_in[10];
  const float* ba    = (const float*)d_in[11];
  float* out = (float*)d_out;

  char* w = (char*)d_ws;
  float* cpt = (float*)w;                      w += (size_t)BC * 128 * 4;
  float* cp1 = (float*)w;                      w += (size_t)BC * 128 * 4;
  float* cj2 = (float*)w;                      w += (size_t)BC * 128 * 4;
  unsigned short* W2sw  = (unsigned short*)w;  w += 32 * 64 * 8 * 2;     // 32 KB
  unsigned short* Wcsw  = (unsigned short*)w;  w += 32 * 64 * 8 * 2;     // 32 KB
  unsigned short* WaggT = (unsigned short*)w;  w += 128 * 512 * 2;       // 128 KB
  unsigned short* aggb  = (unsigned short*)w;  w += (size_t)BC * 512 * 2;
  int* tidx = (int*)w;                         w += 16 * 128 * 4;
  int* cidx = (int*)w;                         w += 16 * 128 * 4;
  int* tcnt = (int*)w;                         w += 16 * 4;
  int* ccnt = (int*)w;                         w += 16 * 4;

  prep_kernel<<<305, 256, 0, stream>>>(Wt, Wc, Wa, clone, food, bt, bcl,
                                       tmask, cmask,
                                       W2sw, Wcsw, WaggT, cpt, cp1, cj2, aggb,
                                       tidx, tcnt, cidx, ccnt);
  branch11<<<512, 512, 0, stream>>>(trel, crel, cpt, cp1, cj2,
                                    tidx, tcnt, cidx, ccnt,
                                    (const uint4*)W2sw, (const uint4*)Wcsw, aggb);
  final_kernel<<<128, 256, 0, stream>>>(aggb, WaggT, clone, ba, out);
}

// Round 13
// 69.408 us; speedup vs baseline: 2.4278x; 1.0641x over previous
//
#include <hip/hip_runtime.h>

#define BB 16
#define CC 128
#define TT 128
#define HH 128
#define BC (BB*CC)   // 2048

typedef __attribute__((ext_vector_type(8))) short bf16x8;
typedef __attribute__((ext_vector_type(4))) float f32x4;

__device__ __forceinline__ unsigned short f2bf(float f) {
  union { float f; unsigned u; } v; v.f = f;
  unsigned u = v.u;
  u += 0x7FFFu + ((u >> 16) & 1u);   // round-to-nearest-even
  return (unsigned short)(u >> 16);
}

__device__ __forceinline__ bf16x8 pack8(f32x4 a, f32x4 b) {
  bf16x8 r;
  r[0] = (short)f2bf(a[0]); r[1] = (short)f2bf(a[1]);
  r[2] = (short)f2bf(a[2]); r[3] = (short)f2bf(a[3]);
  r[4] = (short)f2bf(b[0]); r[5] = (short)f2bf(b[1]);
  r[6] = (short)f2bf(b[2]); r[7] = (short)f2bf(b[3]);
  return r;
}

__device__ __forceinline__ float bf2f(unsigned short u) {
  union { unsigned u; float f; } v; v.u = ((unsigned)u) << 16; return v.f;
}

// ---- prep (unchanged, validated) --------------------------------------------
__global__ __launch_bounds__(256) void prep_kernel(
    const float* __restrict__ Wt, const float* __restrict__ Wc, const float* __restrict__ Wa,
    const float* __restrict__ clone, const float* __restrict__ food,
    const float* __restrict__ bt, const float* __restrict__ bcl,
    const int* __restrict__ tmask, const int* __restrict__ cmask,
    unsigned short* __restrict__ W2sw, unsigned short* __restrict__ Wcsw,
    unsigned short* __restrict__ WaggT,
    float* __restrict__ cpt, float* __restrict__ cp1, float* __restrict__ cj2,
    unsigned short* __restrict__ agg,
    int* __restrict__ tidx, int* __restrict__ tcnt,
    int* __restrict__ cidx, int* __restrict__ ccnt) {
  const int blk = blockIdx.x, tid = threadIdx.x;
  if (blk < 48) {
    int i = blk * 256 + tid;
    if (i < 2048) {                       // thorn frags: 32 frags x 64 lanes
      int f = i >> 6, l = i & 63;
      int kt = f >> 3, n = f & 7;
      int ncol = n * 16 + (l & 15);
      int k0 = kt * 32 + (l >> 4) * 8;
      unsigned short o[8];
      #pragma unroll
      for (int e = 0; e < 8; ++e) o[e] = f2bf(Wt[(128 + k0 + e) * 128 + ncol]);
      *(uint4*)&W2sw[i * 8] = *(uint4*)o;
    } else if (i < 4096) {                // clone W3 frags: 32 frags x 64 lanes
      int j = i - 2048;
      int f = j >> 6, l = j & 63;
      int kt = f >> 3, n = f & 7;
      int ncol = n * 16 + (l & 15);
      int k0 = kt * 32 + (l >> 4) * 8;
      unsigned short o[8];
      #pragma unroll
      for (int e = 0; e < 8; ++e) o[e] = f2bf(Wc[(256 + k0 + e) * 128 + ncol]);
      *(uint4*)&Wcsw[j * 8] = *(uint4*)o;
    } else {                              // agg weights, plain [n][k] transpose
      int j = i - 4096;                   // [0, 8192)
      int n = j >> 6, k0 = (j & 63) * 8;
      unsigned short o[8];
      #pragma unroll
      for (int e = 0; e < 8; ++e) o[e] = f2bf(Wa[(k0 + e) * 128 + n]);
      *(uint4*)&WaggT[n * 512 + k0] = *(uint4*)o;
    }
  } else if (blk < 304) {
    // bias rows: 8 bc rows per block; 3 GEMVs per element
    const int bc0 = (blk - 48) * 8;
    __shared__ float cl[8][128];
    for (int i = tid; i < 1024; i += 256) cl[i >> 7][i & 127] = clone[bc0 * 128 + i];
    __syncthreads();
    const int k = tid & 127, r0 = (tid >> 7) * 4;
    float s1[4], s2[4], s3[4];
    #pragma unroll
    for (int r = 0; r < 4; ++r) { s1[r] = bt[k]; s2[r] = bcl[k]; s3[r] = 0.f; }
    #pragma unroll 4
    for (int h = 0; h < 128; ++h) {
      float w1 = Wt[h * 128 + k], w2 = Wc[h * 128 + k], w3 = Wc[(128 + h) * 128 + k];
      #pragma unroll
      for (int r = 0; r < 4; ++r) {
        float c = cl[r0 + r][h];
        s1[r] = fmaf(c, w1, s1[r]);
        s2[r] = fmaf(c, w2, s2[r]);
        s3[r] = fmaf(c, w3, s3[r]);
      }
    }
    #pragma unroll
    for (int r = 0; r < 4; ++r) {
      cpt[(bc0 + r0 + r) * 128 + k] = s1[r];
      cp1[(bc0 + r0 + r) * 128 + k] = s2[r];
      cj2[(bc0 + r0 + r) * 128 + k] = s3[r];
    }
    for (int i = tid; i < 1024; i += 256) {
      int r = i >> 7, kk = i & 127;
      agg[(size_t)(bc0 + r) * 512 + kk]       = f2bf(cl[r][kk]);
      agg[(size_t)(bc0 + r) * 512 + 128 + kk] = f2bf(food[bc0 * 128 + i]);
    }
  } else {
    // mask compaction: thread i<32: b=i>>1, which=i&1; serial scan of 128 entries
    if (tid < 32) {
      int b = tid >> 1, which = tid & 1;
      const int* m = which ? cmask : tmask;
      int* idx = which ? cidx : tidx;
      int c = 0;
      for (int i = 0; i < 128; ++i)
        if (m[b * 128 + i]) idx[b * 128 + c++] = i;
      if (which) ccnt[b] = c; else tcnt[b] = c;
    }
  }
}

// ---- fused branch kernel: blocks 0..255 clone, 256..511 thorn --------------
// BARRIER-FREE wave-owns-tile: wave w exclusively computes tile bc0+w via a
// STATIC 8-iteration row-group loop with wave-uniform skip (rg*16 >= cnt).
// No per-tile __syncthreads -> waves drift out of phase, hiding each other's
// HBM latency (the phase-lock was the 3x gap). Per-wave shfl max + direct
// agg store. Compaction gather + cj2 epilogue unchanged from branch9.
__global__ __launch_bounds__(512, 4) void branch13(
    const float* __restrict__ trel, const float* __restrict__ crel,
    const float* __restrict__ cpt, const float* __restrict__ cp1,
    const float* __restrict__ cj2,
    const int* __restrict__ tidx, const int* __restrict__ tcnt,
    const int* __restrict__ cidx, const int* __restrict__ ccnt,
    const uint4* __restrict__ W2sw, const uint4* __restrict__ Wcsw,
    unsigned short* __restrict__ agg) {
  __shared__ uint4 Wlds[32 * 64];              // 32 KB
  __shared__ unsigned short cj2l[128][130];    // 32.5 KB, transposed [col][row]+pad
  __shared__ int idxl[128];

  const bool isClone = blockIdx.x < 256;
  const int tileIdx = blockIdx.x & 255;
  const float* __restrict__ rel     = isClone ? crel  : trel;
  const float* __restrict__ biasrow = isClone ? cp1   : cpt;
  const int*   __restrict__ idxg    = isClone ? cidx  : tidx;
  const uint4* __restrict__ Wsw     = isClone ? Wcsw  : W2sw;
  const int aggoff = isClone ? 384 : 256;

  const int tid = threadIdx.x;
  const int wave = tid >> 6, lane = tid & 63;
  const int l16 = lane & 15, lk = lane >> 4;
  const int bc0 = tileIdx << 3;               // 8 tiles per block
  const int b = bc0 >> 7;                     // same b for all 8 tiles
  const int cnt = (isClone ? ccnt : tcnt)[b];
  const int cl  = cnt > 0 ? cnt : 1;

  for (int i = tid; i < 2048; i += 512) Wlds[i] = Wsw[i];
  if (tid < 128) idxl[tid] = idxg[b * 128 + tid];
  if (isClone) {                              // stage cj2[b] transposed as bf16
    const float* cg = cj2 + (size_t)b * 128 * 128;
    for (int i = tid; i < 2048; i += 512) {
      int r = i >> 4, c8 = (i & 15) * 8;
      f32x4 a0 = *(const f32x4*)(cg + r * 128 + c8);
      f32x4 a1 = *(const f32x4*)(cg + r * 128 + c8 + 4);
      bf16x8 p = pack8(a0, a1);
      #pragma unroll
      for (int e = 0; e < 8; ++e) cj2l[c8 + e][r] = (unsigned short)p[e];
    }
  }
  __syncthreads();                            // ONLY barrier in the kernel

  const int bc = bc0 + wave;                  // this wave's tile
  const float* Rb = rel + (size_t)bc * 16384 + lk * 8;

  float bias[8];
  #pragma unroll
  for (int n = 0; n < 8; ++n) bias[n] = biasrow[bc * 128 + n * 16 + l16];

  float vmax[8];
  #pragma unroll
  for (int n = 0; n < 8; ++n) vmax[n] = 0.f;

  #pragma unroll 1
  for (int rg = 0; rg < 8; ++rg) {
    if ((rg << 4) < cnt) {                    // wave-uniform guard
      // gathered A rows for this row-group (demand-loaded f32 -> bf16)
      int rs = (rg << 4) + l16; if (rs >= cl) rs = cl - 1;
      const float* Rt = Rb + idxl[rs] * 128;
      bf16x8 afr[4];
      #pragma unroll
      for (int kt = 0; kt < 4; ++kt)
        afr[kt] = pack8(*(const f32x4*)(Rt + kt * 32),
                        *(const f32x4*)(Rt + kt * 32 + 4));

      f32x4 acc[8];
      #pragma unroll
      for (int n = 0; n < 8; ++n) acc[n] = (f32x4){0.f, 0.f, 0.f, 0.f};
      #pragma unroll
      for (int kt = 0; kt < 4; ++kt) {
        #pragma unroll
        for (int n = 0; n < 8; ++n) {
          bf16x8 bfr = *(const bf16x8*)&Wlds[(kt * 8 + n) * 64 + lane];
          acc[n] = __builtin_amdgcn_mfma_f32_16x16x32_bf16(afr[kt], bfr, acc[n], 0, 0, 0);
        }
      }

      if (isClone) {
        int rowj[4];                          // C/D row = lk*4+j (m89 layout)
        #pragma unroll
        for (int j = 0; j < 4; ++j) {
          int rj = (rg << 4) + lk * 4 + j; if (rj >= cl) rj = cl - 1;
          rowj[j] = idxl[rj];
        }
        #pragma unroll
        for (int n = 0; n < 8; ++n) {
          const int col = n * 16 + l16;
          #pragma unroll
          for (int j = 0; j < 4; ++j) {
            float x = acc[n][j] + bias[n] + bf2f(cj2l[col][rowj[j]]);
            vmax[n] = fmaxf(vmax[n], fmaxf(x, 0.f));
          }
        }
      } else {
        #pragma unroll
        for (int n = 0; n < 8; ++n) {
          #pragma unroll
          for (int j = 0; j < 4; ++j)
            vmax[n] = fmaxf(vmax[n], fmaxf(acc[n][j] + bias[n], 0.f));
        }
      }
    }
  }

  // per-wave reduction, direct store (no block barrier)
  unsigned short* aggw = agg + (size_t)bc * 512 + aggoff;
  #pragma unroll
  for (int n = 0; n < 8; ++n) {
    float v = vmax[n];
    v = fmaxf(v, __shfl_xor(v, 16));
    v = fmaxf(v, __shfl_xor(v, 32));
    if (lane < 16) aggw[n * 16 + lane] = f2bf(v);
  }
}

// ---- final: out = clone + relu(agg(2048x512) @ W_agg + b_agg) --------------
__global__ __launch_bounds__(256) void final_kernel(
    const unsigned short* __restrict__ agg, const unsigned short* __restrict__ WaggT,
    const float* __restrict__ clone, const float* __restrict__ bagg,
    float* __restrict__ out) {
  const int tid = threadIdx.x;
  const int wave = tid >> 6, lane = tid & 63;
  const int l16 = lane & 15, lk = lane >> 4;
  const int mrow = blockIdx.x * 16;

  f32x4 acc[2];
  acc[0] = (f32x4){0.f, 0.f, 0.f, 0.f};
  acc[1] = (f32x4){0.f, 0.f, 0.f, 0.f};
  #pragma unroll
  for (int kt = 0; kt < 16; ++kt) {
    bf16x8 a = *(const bf16x8*)(agg + (size_t)(mrow + l16) * 512 + kt * 32 + lk * 8);
    #pragma unroll
    for (int nn = 0; nn < 2; ++nn) {
      int ncol = (wave * 2 + nn) * 16 + l16;
      bf16x8 bfr = *(const bf16x8*)(WaggT + (size_t)ncol * 512 + kt * 32 + lk * 8);
      acc[nn] = __builtin_amdgcn_mfma_f32_16x16x32_bf16(a, bfr, acc[nn], 0, 0, 0);
    }
  }
  #pragma unroll
  for (int nn = 0; nn < 2; ++nn) {
    int col = (wave * 2 + nn) * 16 + l16;
    float bias = bagg[col];
    #pragma unroll
    for (int j = 0; j < 4; ++j) {
      int row = mrow + lk * 4 + j;
      out[row * 128 + col] = clone[row * 128 + col] + fmaxf(acc[nn][j] + bias, 0.f);
    }
  }
}

extern "C" void kernel_launch(void* const* d_in, const int* in_sizes, int n_in,
                              void* d_out, int out_size, void* d_ws, size_t ws_size,
                              hipStream_t stream) {
  const float* food  = (const float*)d_in[0];
  const float* trel  = (const float*)d_in[1];
  const float* clone = (const float*)d_in[2];
  const float* crel  = (const float*)d_in[3];
  const int*   tmask = (const int*)d_in[4];
  const int*   cmask = (const int*)d_in[5];
  const float* Wt    = (const float*)d_in[6];
  const float* bt    = (const float*)d_in[7];
  const float* Wc    = (const float*)d_in[8];
  const float* bcl   = (const float*)d_in[9];
  const float* Wa    = (const float*)d_in[10];
  const float* ba    = (const float*)d_in[11];
  float* out = (float*)d_out;

  char* w = (char*)d_ws;
  float* cpt = (float*)w;                      w += (size_t)BC * 128 * 4;
  float* cp1 = (float*)w;                      w += (size_t)BC * 128 * 4;
  float* cj2 = (float*)w;                      w += (size_t)BC * 128 * 4;
  unsigned short* W2sw  = (unsigned short*)w;  w += 32 * 64 * 8 * 2;     // 32 KB
  unsigned short* Wcsw  = (unsigned short*)w;  w += 32 * 64 * 8 * 2;     // 32 KB
  unsigned short* WaggT = (unsigned short*)w;  w += 128 * 512 * 2;       // 128 KB
  unsigned short* aggb  = (unsigned short*)w;  w += (size_t)BC * 512 * 2;
  int* tidx = (int*)w;                         w += 16 * 128 * 4;
  int* cidx = (int*)w;                         w += 16 * 128 * 4;
  int* tcnt = (int*)w;                         w += 16 * 4;
  int* ccnt = (int*)w;                         w += 16 * 4;

  prep_kernel<<<305, 256, 0, stream>>>(Wt, Wc, Wa, clone, food, bt, bcl,
                                       tmask, cmask,
                                       W2sw, Wcsw, WaggT, cpt, cp1, cj2, aggb,
                                       tidx, tcnt, cidx, ccnt);
  branch13<<<512, 512, 0, stream>>>(trel, crel, cpt, cp1, cj2,
                                    tidx, tcnt, cidx, ccnt,
                                    (const uint4*)W2sw, (const uint4*)Wcsw, aggb);
  final_kernel<<<128, 256, 0, stream>>>(aggb, WaggT, clone, ba, out);
}